// Round 1
// baseline (3550.787 us; speedup 1.0000x reference)
//
#include <hip/hip_runtime.h>
#include <stdint.h>

typedef unsigned long long u64;

#define N_ROWS 8192
#define D_IN   4096
#define D_OUT  4096
#define KW     (D_IN / 64)   // 64 u64 words per row
#define BM 128
#define BN 128
#define KC 8                 // u64 words per K-chunk (512 bits)
#define NCHUNK (KW / KC)     // 8

// -------- Pass 1: pack sign bits. Each wave: 256 consecutive floats -> 4 u64.
// Bit order is an interleaved permutation of k, identical for x and w, which
// is fine because the dot product is invariant to a common k-permutation.
__global__ __launch_bounds__(256) void pack_signs_kernel(
    const float* __restrict__ in, u64* __restrict__ out, int n_groups) {
  const int wid  = (blockIdx.x * blockDim.x + threadIdx.x) >> 6;
  const int lane = threadIdx.x & 63;
  const int nw   = (gridDim.x * blockDim.x) >> 6;
  for (int g = wid; g < n_groups; g += nw) {
    float4 v = reinterpret_cast<const float4*>(in)[(size_t)g * 64 + lane];
    u64 b0 = __ballot(v.x > 0.0f);
    u64 b1 = __ballot(v.y > 0.0f);
    u64 b2 = __ballot(v.z > 0.0f);
    u64 b3 = __ballot(v.w > 0.0f);
    if (lane < 4) {
      u64 w = (lane == 0) ? b0 : (lane == 1) ? b1 : (lane == 2) ? b2 : b3;
      out[(size_t)g * 4 + lane] = w;
    }
  }
}

// -------- Pass 2: XNOR-popcount GEMM. dot = K - 2*popcount(xb ^ wb).
// 128x128 block tile, 8x8 per thread, LDS-staged chunks of 8 u64 per row.
// LDS word-slot swizzle: slot = kk ^ ((row>>3)&7) so reads are broadcast /
// 2-way at worst.
__global__ __launch_bounds__(256) void bgemm_pop_kernel(
    const u64* __restrict__ xb, const u64* __restrict__ wb,
    const float* __restrict__ bias, float* __restrict__ y) {
  __shared__ u64 xs[BM * KC];
  __shared__ u64 ws[BN * KC];

  const int tid = threadIdx.x;
  const int tx  = tid & 15;   // w-row group (8 rows each)
  const int ty  = tid >> 4;   // x-row group (8 rows each)
  const int m0  = blockIdx.y * BM;
  const int n0  = blockIdx.x * BN;

  unsigned acc[8][8];
#pragma unroll
  for (int i = 0; i < 8; ++i)
#pragma unroll
    for (int j = 0; j < 8; ++j) acc[i][j] = 0u;

  const int ldrow  = tid >> 1;  // 0..127
  const int ldhalf = tid & 1;   // 0..1
  const int s_st   = (ldrow >> 3) & 7;
  const int kb     = ldhalf * 4;

  for (int kc = 0; kc < NCHUNK; ++kc) {
    // cooperative staging: each thread loads 4 u64 of x and 4 u64 of w
    {
      const u64* srcx = xb + (size_t)(m0 + ldrow) * KW + kc * KC + kb;
      u64 a0 = srcx[0], a1 = srcx[1], a2 = srcx[2], a3 = srcx[3];
      xs[ldrow * KC + ((kb + 0) ^ s_st)] = a0;
      xs[ldrow * KC + ((kb + 1) ^ s_st)] = a1;
      xs[ldrow * KC + ((kb + 2) ^ s_st)] = a2;
      xs[ldrow * KC + ((kb + 3) ^ s_st)] = a3;
      const u64* srcw = wb + (size_t)(n0 + ldrow) * KW + kc * KC + kb;
      u64 b0 = srcw[0], b1 = srcw[1], b2 = srcw[2], b3 = srcw[3];
      ws[ldrow * KC + ((kb + 0) ^ s_st)] = b0;
      ws[ldrow * KC + ((kb + 1) ^ s_st)] = b1;
      ws[ldrow * KC + ((kb + 2) ^ s_st)] = b2;
      ws[ldrow * KC + ((kb + 3) ^ s_st)] = b3;
    }
    __syncthreads();

#pragma unroll
    for (int kk = 0; kk < KC; ++kk) {
      u64 xw[8], ww[8];
#pragma unroll
      for (int i = 0; i < 8; ++i)
        xw[i] = xs[(ty * 8 + i) * KC + (kk ^ (ty & 7))];
#pragma unroll
      for (int j = 0; j < 8; ++j)
        ww[j] = ws[(tx * 8 + j) * KC + (kk ^ (tx & 7))];
#pragma unroll
      for (int i = 0; i < 8; ++i)
#pragma unroll
        for (int j = 0; j < 8; ++j) {
          u64 v = xw[i] ^ ww[j];
          // write as two 32-bit popcounts with separate adds so LLVM can
          // fuse each into v_bcnt_u32_b32's accumulate operand (4 VALU/word)
          acc[i][j] = __builtin_popcount((unsigned)v) + acc[i][j];
          acc[i][j] = __builtin_popcount((unsigned)(v >> 32)) + acc[i][j];
        }
    }
    __syncthreads();
  }

  // epilogue: y = K - 2*popXor + bias, vectorized float4 stores
  float bv[8];
#pragma unroll
  for (int j = 0; j < 8; ++j) bv[j] = bias[n0 + tx * 8 + j];

#pragma unroll
  for (int i = 0; i < 8; ++i) {
    float* orow = y + (size_t)(m0 + ty * 8 + i) * D_OUT + n0 + tx * 8;
    float4 o0, o1;
    o0.x = (float)(D_IN - 2 * (int)acc[i][0]) + bv[0];
    o0.y = (float)(D_IN - 2 * (int)acc[i][1]) + bv[1];
    o0.z = (float)(D_IN - 2 * (int)acc[i][2]) + bv[2];
    o0.w = (float)(D_IN - 2 * (int)acc[i][3]) + bv[3];
    o1.x = (float)(D_IN - 2 * (int)acc[i][4]) + bv[4];
    o1.y = (float)(D_IN - 2 * (int)acc[i][5]) + bv[5];
    o1.z = (float)(D_IN - 2 * (int)acc[i][6]) + bv[6];
    o1.w = (float)(D_IN - 2 * (int)acc[i][7]) + bv[7];
    reinterpret_cast<float4*>(orow)[0] = o0;
    reinterpret_cast<float4*>(orow)[1] = o1;
  }
}

extern "C" void kernel_launch(void* const* d_in, const int* in_sizes, int n_in,
                              void* d_out, int out_size, void* d_ws, size_t ws_size,
                              hipStream_t stream) {
  const float* x    = (const float*)d_in[0];
  const float* w    = (const float*)d_in[1];
  const float* bias = (const float*)d_in[2];
  float* y = (float*)d_out;

  u64* xb = (u64*)d_ws;                       // 8192*64*8 = 4 MB
  u64* wb = xb + (size_t)N_ROWS * KW;         // 4096*64*8 = 2 MB

  const int xg = (N_ROWS * D_IN) / 256;  // 131072 groups
  const int wg = (D_OUT * D_IN) / 256;   // 65536 groups
  pack_signs_kernel<<<2048, 256, 0, stream>>>(x, xb, xg);
  pack_signs_kernel<<<1024, 256, 0, stream>>>(w, wb, wg);

  dim3 grid(D_OUT / BN, N_ROWS / BM);
  bgemm_pop_kernel<<<grid, 256, 0, stream>>>(xb, wb, bias, y);
}

// Round 2
// 211.511 us; speedup vs baseline: 16.7877x; 16.7877x over previous
//
#include <hip/hip_runtime.h>
#include <stdint.h>

typedef unsigned long long u64;
using i32x4 = __attribute__((ext_vector_type(4))) int;

#define M_ROWS 8192
#define N_COLS 4096
#define K_DIM  4096
#define BM 128
#define BN 128
#define BK 64
#define NSTEP (K_DIM / BK)

// ---------------- Pass 1: binarize f32 -> i8 {+1,-1} ----------------
__global__ __launch_bounds__(256) void binarize_i8_kernel(
    const float4* __restrict__ in, int* __restrict__ out, int n4) {
  int idx = blockIdx.x * blockDim.x + threadIdx.x;
  int stride = gridDim.x * blockDim.x;
  for (int i = idx; i < n4; i += stride) {
    float4 v = in[i];
    int p = (v.x > 0.f ? 0x01 : 0xFF)
          | ((v.y > 0.f ? 0x01 : 0xFF) << 8)
          | ((v.z > 0.f ? 0x01 : 0xFF) << 16)
          | ((v.w > 0.f ? 0x01 : 0xFF) << 24);
    out[i] = p;
  }
}

// ---------------- global -> LDS direct (16B per lane) ----------------
__device__ __forceinline__ void gload16(const void* g, void* l) {
  __builtin_amdgcn_global_load_lds(
      (const __attribute__((address_space(1))) void*)g,
      (__attribute__((address_space(3))) void*)l,
      16, 0, 0);
}

// ---------------- Pass 2: i8 MFMA GEMM (m97 structure) ----------------
// y[m][n] = sum_k xa[m][k]*wb[n][k]  (B^T layout: wb rows are output cols)
// LDS tiles [128 rows][64 bytes], 16B slots XOR-swizzled: LDS row r slot s
// holds global slot (s ^ (r&3)). gload_lds writes linearly, so the swizzle
// is applied on the per-lane GLOBAL source address (rule #21), and undone
// on the ds_read side.
__global__ __launch_bounds__(256, 2) void bgemm_i8_kernel(
    const signed char* __restrict__ xa, const signed char* __restrict__ wb,
    const float* __restrict__ bias, float* __restrict__ y) {
  __shared__ __align__(16) signed char As[BM * BK];  // 8 KB
  __shared__ __align__(16) signed char Bs[BN * BK];  // 8 KB

  const int tid  = threadIdx.x;
  const int lane = tid & 63;
  const int w    = tid >> 6;      // wave 0..3
  const int wr   = w >> 1;        // wave row 0..1 (64 rows each)
  const int wc   = w & 1;         // wave col 0..1 (64 cols each)
  const int m0   = blockIdx.y * BM;
  const int n0   = blockIdx.x * BN;

  i32x4 acc[4][4];
#pragma unroll
  for (int m = 0; m < 4; ++m)
#pragma unroll
    for (int n = 0; n < 4; ++n) acc[m][n] = (i32x4){0, 0, 0, 0};

  // staging geometry: thread t covers LDS bytes [t*16, t*16+16) per pass.
  // pass p in {0,1}: dest row r = p*64 + t/4, dest slot s = t&3.
  const int r0 = tid >> 2;                  // 0..63
  const int s0 = tid & 3;
  const int sw = (s0 ^ (r0 & 3)) << 4;      // swizzled source slot offset

  const signed char* aSrc0 = xa + (size_t)(m0 + r0)      * K_DIM + sw;
  const signed char* aSrc1 = xa + (size_t)(m0 + 64 + r0) * K_DIM + sw;
  const signed char* bSrc0 = wb + (size_t)(n0 + r0)      * K_DIM + sw;
  const signed char* bSrc1 = wb + (size_t)(n0 + 64 + r0) * K_DIM + sw;

  // wave-uniform LDS destinations (HW adds lane*16)
  signed char* aDst0 = As + w * 1024;
  signed char* aDst1 = As + 4096 + w * 1024;
  signed char* bDst0 = Bs + w * 1024;
  signed char* bDst1 = Bs + 4096 + w * 1024;

  const int lr = lane & 15;   // row within 16x16 fragment
  const int kq = lane >> 4;   // k-quarter 0..3 (16 bytes each)
  const int rdsw = ((kq ^ (lr & 3)) << 4);  // swizzled read slot offset

  for (int kc = 0; kc < NSTEP; ++kc) {
    const size_t ko = (size_t)kc * BK;
    gload16(aSrc0 + ko, aDst0);
    gload16(aSrc1 + ko, aDst1);
    gload16(bSrc0 + ko, bDst0);
    gload16(bSrc1 + ko, bDst1);
    __syncthreads();   // drains vmcnt -> staged tile visible

    i32x4 af[4], bf[4];
#pragma unroll
    for (int m = 0; m < 4; ++m) {
      const int row = wr * 64 + m * 16 + lr;       // row&3 == lr&3
      af[m] = *(const i32x4*)(As + row * BK + rdsw);
    }
#pragma unroll
    for (int n = 0; n < 4; ++n) {
      const int row = wc * 64 + n * 16 + lr;
      bf[n] = *(const i32x4*)(Bs + row * BK + rdsw);
    }
#pragma unroll
    for (int m = 0; m < 4; ++m)
#pragma unroll
      for (int n = 0; n < 4; ++n)
        acc[m][n] = __builtin_amdgcn_mfma_i32_16x16x64_i8(af[m], bf[n], acc[m][n], 0, 0, 0);
    __syncthreads();   // before next stage overwrites the tile
  }

  // epilogue: C/D layout col = lane&15, row = (lane>>4)*4 + j (verified map)
  float bv[4];
#pragma unroll
  for (int n = 0; n < 4; ++n) bv[n] = bias[n0 + wc * 64 + n * 16 + lr];

#pragma unroll
  for (int m = 0; m < 4; ++m) {
#pragma unroll
    for (int j = 0; j < 4; ++j) {
      const int gr = m0 + wr * 64 + m * 16 + kq * 4 + j;
      float* orow = y + (size_t)gr * N_COLS + n0 + wc * 64 + lr;
#pragma unroll
      for (int n = 0; n < 4; ++n)
        orow[n * 16] = (float)acc[m][n][j] + bv[n];
    }
  }
}

// ================= fallback (only if ws too small): packed popcount ======
#define KW (K_DIM / 64)
#define KC 8
#define NCHUNK (KW / KC)

__global__ __launch_bounds__(256) void pack_signs_kernel(
    const float* __restrict__ in, u64* __restrict__ out, int n_groups) {
  const int wid  = (blockIdx.x * blockDim.x + threadIdx.x) >> 6;
  const int lane = threadIdx.x & 63;
  const int nw   = (gridDim.x * blockDim.x) >> 6;
  for (int g = wid; g < n_groups; g += nw) {
    float4 v = reinterpret_cast<const float4*>(in)[(size_t)g * 64 + lane];
    u64 b0 = __ballot(v.x > 0.0f);
    u64 b1 = __ballot(v.y > 0.0f);
    u64 b2 = __ballot(v.z > 0.0f);
    u64 b3 = __ballot(v.w > 0.0f);
    if (lane < 4) {
      u64 wv = (lane == 0) ? b0 : (lane == 1) ? b1 : (lane == 2) ? b2 : b3;
      out[(size_t)g * 4 + lane] = wv;
    }
  }
}

__global__ __launch_bounds__(256, 4) void bgemm_pop_kernel(
    const u64* __restrict__ xb, const u64* __restrict__ wbp,
    const float* __restrict__ bias, float* __restrict__ y) {
  __shared__ u64 xs[BM * KC];
  __shared__ u64 ws[BN * KC];
  const int tid = threadIdx.x;
  const int tx  = tid & 15;
  const int ty  = tid >> 4;
  const int m0  = blockIdx.y * BM;
  const int n0  = blockIdx.x * BN;
  unsigned acc[8][8];
#pragma unroll
  for (int i = 0; i < 8; ++i)
#pragma unroll
    for (int j = 0; j < 8; ++j) acc[i][j] = 0u;
  const int ldrow = tid >> 1, ldhalf = tid & 1;
  const int s_st = (ldrow >> 3) & 7, kb = ldhalf * 4;
  for (int kc = 0; kc < NCHUNK; ++kc) {
    const u64* srcx = xb + (size_t)(m0 + ldrow) * KW + kc * KC + kb;
    const u64* srcw = wbp + (size_t)(n0 + ldrow) * KW + kc * KC + kb;
#pragma unroll
    for (int t = 0; t < 4; ++t) xs[ldrow * KC + ((kb + t) ^ s_st)] = srcx[t];
#pragma unroll
    for (int t = 0; t < 4; ++t) ws[ldrow * KC + ((kb + t) ^ s_st)] = srcw[t];
    __syncthreads();
#pragma unroll 1
    for (int kk = 0; kk < KC; ++kk) {
      u64 wwv[8];
#pragma unroll
      for (int j = 0; j < 8; ++j)
        wwv[j] = ws[(tx * 8 + j) * KC + (kk ^ (tx & 7))];
#pragma unroll
      for (int i = 0; i < 8; ++i) {
        u64 xv = xs[(ty * 8 + i) * KC + (kk ^ (ty & 7))];
#pragma unroll
        for (int j = 0; j < 8; ++j) {
          u64 v = xv ^ wwv[j];
          acc[i][j] = __builtin_popcount((unsigned)v) + acc[i][j];
          acc[i][j] = __builtin_popcount((unsigned)(v >> 32)) + acc[i][j];
        }
      }
    }
    __syncthreads();
  }
  float bv[8];
#pragma unroll
  for (int j = 0; j < 8; ++j) bv[j] = bias[n0 + tx * 8 + j];
#pragma unroll
  for (int i = 0; i < 8; ++i) {
    float* orow = y + (size_t)(m0 + ty * 8 + i) * N_COLS + n0 + tx * 8;
#pragma unroll
    for (int j = 0; j < 8; ++j)
      orow[j] = (float)(K_DIM - 2 * (int)acc[i][j]) + bv[j];
  }
}

// =========================================================================
extern "C" void kernel_launch(void* const* d_in, const int* in_sizes, int n_in,
                              void* d_out, int out_size, void* d_ws, size_t ws_size,
                              hipStream_t stream) {
  const float* x    = (const float*)d_in[0];
  const float* wgt  = (const float*)d_in[1];
  const float* bias = (const float*)d_in[2];
  float* y = (float*)d_out;

  const size_t need_i8 = (size_t)(M_ROWS + N_COLS) * K_DIM;  // 50.3 MB
  if (ws_size >= need_i8) {
    signed char* xa = (signed char*)d_ws;
    signed char* wb = xa + (size_t)M_ROWS * K_DIM;
    binarize_i8_kernel<<<2048, 256, 0, stream>>>(
        (const float4*)x, (int*)xa, (M_ROWS * K_DIM) / 4);
    binarize_i8_kernel<<<2048, 256, 0, stream>>>(
        (const float4*)wgt, (int*)wb, (N_COLS * K_DIM) / 4);
    dim3 grid(N_COLS / BN, M_ROWS / BM);
    bgemm_i8_kernel<<<grid, 256, 0, stream>>>(xa, wb, bias, y);
  } else {
    u64* xb = (u64*)d_ws;
    u64* wbp = xb + (size_t)M_ROWS * KW;
    pack_signs_kernel<<<2048, 256, 0, stream>>>(x, xb, (M_ROWS * K_DIM) / 256);
    pack_signs_kernel<<<1024, 256, 0, stream>>>(wgt, wbp, (N_COLS * K_DIM) / 256);
    dim3 grid(N_COLS / BN, M_ROWS / BM);
    bgemm_pop_kernel<<<grid, 256, 0, stream>>>(xb, wbp, bias, y);
  }
}

// Round 3
// 191.857 us; speedup vs baseline: 18.5075x; 1.1024x over previous
//
#include <hip/hip_runtime.h>
#include <stdint.h>

using i32x4 = __attribute__((ext_vector_type(4))) int;

#define M_ROWS 8192
#define N_COLS 4096
#define K_DIM  4096          // K in elements == bytes per packed i8 row
#define BM 256
#define BN 256
#define TK 128               // K-bytes per tile
#define NT (K_DIM / TK)      // 32 K-tiles

// ---------------- Pass 1: binarize f32 -> i8 {+1,-1} ----------------
__global__ __launch_bounds__(256) void binarize_i8_kernel(
    const float4* __restrict__ in, int* __restrict__ out, int n4) {
  int idx = blockIdx.x * blockDim.x + threadIdx.x;
  int stride = gridDim.x * blockDim.x;
  for (int i = idx; i < n4; i += stride) {
    float4 v = in[i];
    int p = (v.x > 0.f ? 0x01 : 0xFF)
          | ((v.y > 0.f ? 0x01 : 0xFF) << 8)
          | ((v.z > 0.f ? 0x01 : 0xFF) << 16)
          | ((v.w > 0.f ? 0x01 : 0xFF) << 24);
    out[i] = p;
  }
}

// ---------------- global -> LDS direct (16B per lane) ----------------
#define GLOAD(gsrc, ldst)                                                    \
  __builtin_amdgcn_global_load_lds(                                          \
      (const __attribute__((address_space(1))) void*)(gsrc),                 \
      (__attribute__((address_space(3))) void*)(ldst), 16, 0, 0)

// ---------------- Pass 2: i8 MFMA GEMM, 256^2 8-phase schedule --------
// LDS per operand: [2 buf][2 khalf][256 rows][64 B] = 64 KB (A) + 64 KB (B).
// Swizzle: LDS cell (row, slot) holds global 16B-slot (slot ^ ((row>>1)&3))
// of that row's K-half. Applied on the global source (gload_lds writes
// linearly), undone on the ds_read side -> conflict-free b128 reads.
// Stage units (256 rows x one K-half = 2 gload16/thread) are LDS-contiguous.
// Schedule per K-tile: 4 phases {stage 1 unit of t+1; ds_read subtile;
// barrier; 16 MFMA (setprio); [vmcnt(4)]; barrier}, counted vmcnt never 0
// in the main loop (2-unit pipeline lead).

#define STG_A(NB, KB, KH)                                                    \
  GLOAD(aS0 + (KB) + (KH) * 64, As + (NB) + (KH) * 16384 + dstW);            \
  GLOAD(aS1 + (KB) + (KH) * 64, As + (NB) + (KH) * 16384 + 8192 + dstW)

#define STG_B(NB, KB, KH)                                                    \
  GLOAD(bS0 + (KB) + (KH) * 64, Bs + (NB) + (KH) * 16384 + dstW);            \
  GLOAD(bS1 + (KB) + (KH) * 64, Bs + (NB) + (KH) * 16384 + 8192 + dstW)

#define DO_PHASE(BUFOFF, KHOFF, MH, BLOAD, STAGE_STMT, PRE_CLOSE)            \
  {                                                                          \
    STAGE_STMT                                                               \
    if (BLOAD) {                                                             \
      _Pragma("unroll")                                                      \
      for (int nf = 0; nf < 4; ++nf)                                         \
        bf[nf] = *(const i32x4*)(Bs + (BUFOFF) + (KHOFF) + bRdOff +          \
                                 nf * 1024);                                 \
    }                                                                        \
    i32x4 af[4];                                                             \
    _Pragma("unroll")                                                        \
    for (int mf = 0; mf < 4; ++mf)                                           \
      af[mf] = *(const i32x4*)(As + (BUFOFF) + (KHOFF) + aRdOff +            \
                               (MH) * 4096 + mf * 1024);                     \
    __builtin_amdgcn_s_barrier();                                            \
    __builtin_amdgcn_s_setprio(1);                                           \
    _Pragma("unroll")                                                        \
    for (int mf = 0; mf < 4; ++mf) {                                         \
      _Pragma("unroll")                                                      \
      for (int nf = 0; nf < 4; ++nf)                                         \
        acc[(MH) * 4 + mf][nf] = __builtin_amdgcn_mfma_i32_16x16x64_i8(      \
            af[mf], bf[nf], acc[(MH) * 4 + mf][nf], 0, 0, 0);                \
    }                                                                        \
    __builtin_amdgcn_s_setprio(0);                                           \
    PRE_CLOSE                                                                \
    __builtin_amdgcn_s_barrier();                                            \
  }

#define TILE_NORMAL(BUFOFF, NBUFOFF, KB)                                     \
  DO_PHASE(BUFOFF, 0, 0, true, STG_A(NBUFOFF, KB, 0);, )                     \
  DO_PHASE(BUFOFF, 0, 1, false, STG_B(NBUFOFF, KB, 0);,                      \
           asm volatile("s_waitcnt vmcnt(4)" ::: "memory");)                 \
  DO_PHASE(BUFOFF, 16384, 0, true, STG_A(NBUFOFF, KB, 1);, )                 \
  DO_PHASE(BUFOFF, 16384, 1, false, STG_B(NBUFOFF, KB, 1);,                  \
           asm volatile("s_waitcnt vmcnt(4)" ::: "memory");)

#define TILE_LAST(BUFOFF)                                                    \
  DO_PHASE(BUFOFF, 0, 0, true, , )                                           \
  DO_PHASE(BUFOFF, 0, 1, false, ,                                            \
           asm volatile("s_waitcnt vmcnt(0)" ::: "memory");)                 \
  DO_PHASE(BUFOFF, 16384, 0, true, , )                                       \
  DO_PHASE(BUFOFF, 16384, 1, false, , )

__global__ __launch_bounds__(512, 2) void bgemm_i8_8ph(
    const signed char* __restrict__ xa, const signed char* __restrict__ wb,
    const float* __restrict__ bias, float* __restrict__ y) {
  __shared__ __align__(16) signed char As[65536];
  __shared__ __align__(16) signed char Bs[65536];

  const int tid  = threadIdx.x;
  const int lane = tid & 63;
  const int w8   = tid >> 6;   // wave 0..7
  const int wr   = w8 >> 2;    // wave M-row 0..1 (128 rows each)
  const int wc   = w8 & 3;     // wave N-col 0..3 (64 cols each)

  // bijective XCD swizzle (512 blocks, 512 % 8 == 0)
  const int id = blockIdx.x;
  const int sw = ((id & 7) << 6) | (id >> 3);
  const int by = sw >> 4;      // 0..31 M-block
  const int bx = sw & 15;      // 0..15 N-block
  const int m0 = by * BM;
  const int n0 = bx * BN;

  // ---- staging geometry: thread covers LDS row q*128 + tid/4, slot tid&3
  const int r0  = tid >> 2;
  const int gsl = (((tid & 3) ^ ((tid >> 3) & 3)) << 4);  // inverse swizzle
  const signed char* aS0 = xa + (size_t)(m0 + r0) * K_DIM + gsl;
  const signed char* aS1 = xa + (size_t)(m0 + 128 + r0) * K_DIM + gsl;
  const signed char* bS0 = wb + (size_t)(n0 + r0) * K_DIM + gsl;
  const signed char* bS1 = wb + (size_t)(n0 + 128 + r0) * K_DIM + gsl;
  const int dstW = w8 * 1024;  // wave-uniform LDS dest (HW adds lane*16)

  // ---- fragment-read geometry (16x16x64 i8: lane lr = row, kq = 16B k-grp)
  const int lr  = lane & 15;
  const int kq  = lane >> 4;
  const int rsw = (kq ^ ((lr >> 1) & 3)) << 4;   // swizzled read slot
  const int aRdOff = (wr * 128 + lr) * 64 + rsw; // + MH*4096 + mf*1024
  const int bRdOff = (wc * 64 + lr) * 64 + rsw;  // + nf*1024

  i32x4 acc[8][4];
#pragma unroll
  for (int i = 0; i < 8; ++i)
#pragma unroll
    for (int j = 0; j < 4; ++j) acc[i][j] = (i32x4){0, 0, 0, 0};
  i32x4 bf[4];

  // prologue: stage tile 0 (units A0,B0,A1,B1) into buf0; wait first 2 units
  STG_A(0, 0, 0);
  STG_B(0, 0, 0);
  STG_A(0, 0, 1);
  STG_B(0, 0, 1);
  asm volatile("s_waitcnt vmcnt(4)" ::: "memory");
  __builtin_amdgcn_s_barrier();

#pragma unroll 1
  for (int tp = 0; tp < 15; ++tp) {
    const int kb1 = tp * 256 + 128;   // K-byte offset of tile 2tp+1
    const int kb2 = tp * 256 + 256;   // K-byte offset of tile 2tp+2
    TILE_NORMAL(0, 32768, kb1)
    TILE_NORMAL(32768, 0, kb2)
  }
  TILE_NORMAL(0, 32768, 3968)   // tile 30, stages tile 31
  TILE_LAST(32768)              // tile 31

  // epilogue: C/D map col = lane&15, row = kq*4 + j (shape-determined)
  float bv[4];
#pragma unroll
  for (int nf = 0; nf < 4; ++nf) bv[nf] = bias[n0 + wc * 64 + nf * 16 + lr];
#pragma unroll
  for (int fr = 0; fr < 8; ++fr) {
#pragma unroll
    for (int j = 0; j < 4; ++j) {
      const int gr = m0 + wr * 128 + fr * 16 + kq * 4 + j;
      float* orow = y + (size_t)gr * N_COLS + n0 + wc * 64 + lr;
#pragma unroll
      for (int nf = 0; nf < 4; ++nf)
        orow[nf * 16] = (float)acc[fr][nf][j] + bv[nf];
    }
  }
}

// =========================================================================
extern "C" void kernel_launch(void* const* d_in, const int* in_sizes, int n_in,
                              void* d_out, int out_size, void* d_ws, size_t ws_size,
                              hipStream_t stream) {
  const float* x    = (const float*)d_in[0];
  const float* wgt  = (const float*)d_in[1];
  const float* bias = (const float*)d_in[2];
  float* y = (float*)d_out;

  signed char* xab = (signed char*)d_ws;              // 32 MB
  signed char* wbb = xab + (size_t)M_ROWS * K_DIM;    // 16 MB

  binarize_i8_kernel<<<2048, 256, 0, stream>>>(
      (const float4*)x, (int*)xab, (M_ROWS * K_DIM) / 4);
  binarize_i8_kernel<<<2048, 256, 0, stream>>>(
      (const float4*)wgt, (int*)wbb, (N_COLS * K_DIM) / 4);

  bgemm_i8_8ph<<<512, 512, 0, stream>>>(xab, wbb, bias, y);
}

// Round 4
// 131.091 us; speedup vs baseline: 27.0864x; 1.4635x over previous
//
#include <hip/hip_runtime.h>
#include <stdint.h>

using i32x4 = __attribute__((ext_vector_type(4))) int;
using i32x8 = __attribute__((ext_vector_type(8))) int;
using f32x4 = __attribute__((ext_vector_type(4))) float;

#define M_ROWS 8192
#define N_COLS 4096
#define K_DIM  4096
#define KB_ROW 2048          // bytes per packed fp4 row (2 elems/byte)
#define BM 256
#define BN 256
#define TKB 128              // K-bytes per tile (= 256 fp4 elements)
#define NT (KB_ROW / TKB)    // 16 K-tiles
#define SC1 0x7F7F7F7F       // E8M0 = 127 -> scale 1.0, all bytes

// ------------- Pass 1: binarize f32 -> fp4 e2m1 {+1,-1} nibbles -------------
// element 8i+j -> bits [4j+3:4j] of dword i  (byte b = elems 2b,2b+1).
// +1 = 0x2, -1 = 0xA (sign bit = bit 3 of nibble).
__global__ __launch_bounds__(256) void binarize_fp4_kernel(
    const float4* __restrict__ in, unsigned* __restrict__ out, int n_out) {
  int idx = blockIdx.x * blockDim.x + threadIdx.x;
  int stride = gridDim.x * blockDim.x;
  for (int i = idx; i < n_out; i += stride) {
    float4 a = in[2 * i], b = in[2 * i + 1];
    unsigned neg =
        ((a.x > 0.f ? 0u : 1u) << 3)  | ((a.y > 0.f ? 0u : 1u) << 7)  |
        ((a.z > 0.f ? 0u : 1u) << 11) | ((a.w > 0.f ? 0u : 1u) << 15) |
        ((b.x > 0.f ? 0u : 1u) << 19) | ((b.y > 0.f ? 0u : 1u) << 23) |
        ((b.z > 0.f ? 0u : 1u) << 27) | ((b.w > 0.f ? 0u : 1u) << 31);
    out[i] = 0x22222222u | neg;
  }
}

// ---------------- global -> LDS direct (16B per lane) ----------------
#define GLOAD(gsrc, ldst)                                                    \
  __builtin_amdgcn_global_load_lds(                                          \
      (const __attribute__((address_space(1))) void*)(gsrc),                 \
      (__attribute__((address_space(3))) void*)(ldst), 16, 0, 0)

// ---------------- Pass 2: fp4 MFMA GEMM, 256^2 8-phase schedule --------
// Byte-geometry identical to the round-3 i8 kernel: LDS per operand
// [2 buf][2 khalf][256 rows][64 B] = 64 KB; slot-XOR swizzle
// (slot ^ ((row>>1)&3)) applied on the global source, undone on ds_read.
// Each 16x16x128 fp4 MFMA consumes 64 bytes of K per row: one khalf.
// Counted vmcnt(4) twice per tile (4-unit lead), vmcnt(0) only at the end.

#define STG_A(NB, KBo, KH)                                                   \
  GLOAD(aS0 + (KBo) + (KH) * 64, As + (NB) + (KH) * 16384 + dstW);           \
  GLOAD(aS1 + (KBo) + (KH) * 64, As + (NB) + (KH) * 16384 + 8192 + dstW)

#define STG_B(NB, KBo, KH)                                                   \
  GLOAD(bS0 + (KBo) + (KH) * 64, Bs + (NB) + (KH) * 16384 + dstW);           \
  GLOAD(bS1 + (KBo) + (KH) * 64, Bs + (NB) + (KH) * 16384 + 8192 + dstW)

#define DO_PHASE(BUFOFF, KHOFF, MH, BLOAD, STAGE_STMT, PRE_CLOSE)            \
  {                                                                          \
    STAGE_STMT                                                               \
    if (BLOAD) {                                                             \
      _Pragma("unroll")                                                      \
      for (int nf = 0; nf < 4; ++nf)                                         \
        *(i32x4*)&bf8[nf] =                                                  \
            *(const i32x4*)(Bs + (BUFOFF) + (KHOFF) + bRdOff + nf * 1024);   \
    }                                                                        \
    _Pragma("unroll")                                                        \
    for (int mf = 0; mf < 4; ++mf)                                           \
      *(i32x4*)&af8[mf] = *(const i32x4*)(As + (BUFOFF) + (KHOFF) +          \
                                          aRdOff + (MH) * 4096 + mf * 1024); \
    __builtin_amdgcn_s_barrier();                                            \
    __builtin_amdgcn_s_setprio(1);                                           \
    _Pragma("unroll")                                                        \
    for (int mf = 0; mf < 4; ++mf) {                                         \
      _Pragma("unroll")                                                      \
      for (int nf = 0; nf < 4; ++nf)                                         \
        acc[(MH) * 4 + mf][nf] =                                             \
            __builtin_amdgcn_mfma_scale_f32_16x16x128_f8f6f4(                \
                af8[mf], bf8[nf], acc[(MH) * 4 + mf][nf], 4, 4, 0, SC1, 0,   \
                SC1);                                                        \
    }                                                                        \
    __builtin_amdgcn_s_setprio(0);                                           \
    PRE_CLOSE                                                                \
    __builtin_amdgcn_s_barrier();                                            \
  }

#define TILE_NORMAL(BUFOFF, NBUFOFF, KBo)                                    \
  DO_PHASE(BUFOFF, 0, 0, true, STG_A(NBUFOFF, KBo, 0);, )                    \
  DO_PHASE(BUFOFF, 0, 1, false, STG_B(NBUFOFF, KBo, 0);,                     \
           asm volatile("s_waitcnt vmcnt(4)" ::: "memory");)                 \
  DO_PHASE(BUFOFF, 16384, 0, true, STG_A(NBUFOFF, KBo, 1);, )                \
  DO_PHASE(BUFOFF, 16384, 1, false, STG_B(NBUFOFF, KBo, 1);,                 \
           asm volatile("s_waitcnt vmcnt(4)" ::: "memory");)

#define TILE_LAST(BUFOFF)                                                    \
  DO_PHASE(BUFOFF, 0, 0, true, , )                                           \
  DO_PHASE(BUFOFF, 0, 1, false, ,                                            \
           asm volatile("s_waitcnt vmcnt(0)" ::: "memory");)                 \
  DO_PHASE(BUFOFF, 16384, 0, true, , )                                       \
  DO_PHASE(BUFOFF, 16384, 1, false, , )

__global__ __launch_bounds__(512, 2) void bgemm_fp4_8ph(
    const unsigned char* __restrict__ xa, const unsigned char* __restrict__ wb,
    const float* __restrict__ bias, float* __restrict__ y) {
  __shared__ __align__(16) unsigned char As[65536];
  __shared__ __align__(16) unsigned char Bs[65536];

  const int tid  = threadIdx.x;
  const int lane = tid & 63;
  const int w8   = tid >> 6;   // wave 0..7
  const int wr   = w8 >> 2;    // wave M-row 0..1 (128 rows each)
  const int wc   = w8 & 3;     // wave N-col 0..3 (64 cols each)

  // bijective XCD swizzle (512 blocks, 512 % 8 == 0)
  const int id = blockIdx.x;
  const int sw = ((id & 7) << 6) | (id >> 3);
  const int by = sw >> 4;      // 0..31 M-block
  const int bx = sw & 15;      // 0..15 N-block
  const int m0 = by * BM;
  const int n0 = bx * BN;

  // ---- staging geometry: thread covers LDS row tid>>2, slot tid&3
  const int r0  = tid >> 2;
  const int gsl = (((tid & 3) ^ ((tid >> 3) & 3)) << 4);  // inverse swizzle
  const unsigned char* aS0 = xa + (size_t)(m0 + r0) * KB_ROW + gsl;
  const unsigned char* aS1 = xa + (size_t)(m0 + 128 + r0) * KB_ROW + gsl;
  const unsigned char* bS0 = wb + (size_t)(n0 + r0) * KB_ROW + gsl;
  const unsigned char* bS1 = wb + (size_t)(n0 + 128 + r0) * KB_ROW + gsl;
  const int dstW = w8 * 1024;  // wave-uniform LDS dest (HW adds lane*16)

  // ---- fragment-read geometry (16x16x128 fp4: lane lr = row, kq = 16B grp)
  const int lr  = lane & 15;
  const int kq  = lane >> 4;
  const int rsw = (kq ^ ((lr >> 1) & 3)) << 4;   // swizzled read slot
  const int aRdOff = (wr * 128 + lr) * 64 + rsw; // + MH*4096 + mf*1024
  const int bRdOff = (wc * 64 + lr) * 64 + rsw;  // + nf*1024

  f32x4 acc[8][4];
#pragma unroll
  for (int i = 0; i < 8; ++i)
#pragma unroll
    for (int j = 0; j < 4; ++j) acc[i][j] = (f32x4){0.f, 0.f, 0.f, 0.f};

  // fp4 data lives in the LOW 4 regs of the 8-reg operand; high half stays 0
  i32x8 af8[4], bf8[4];
#pragma unroll
  for (int i = 0; i < 4; ++i) {
    af8[i] = (i32x8){0, 0, 0, 0, 0, 0, 0, 0};
    bf8[i] = (i32x8){0, 0, 0, 0, 0, 0, 0, 0};
  }

  // prologue: stage tile 0 (units A0,B0,A1,B1) into buf0; wait first 2 units
  STG_A(0, 0, 0);
  STG_B(0, 0, 0);
  STG_A(0, 0, 1);
  STG_B(0, 0, 1);
  asm volatile("s_waitcnt vmcnt(4)" ::: "memory");
  __builtin_amdgcn_s_barrier();

#pragma unroll 1
  for (int tp = 0; tp < 7; ++tp) {
    const int kb1 = tp * 256 + 128;   // tile 2tp+1
    const int kb2 = tp * 256 + 256;   // tile 2tp+2
    TILE_NORMAL(0, 32768, kb1)
    TILE_NORMAL(32768, 0, kb2)
  }
  TILE_NORMAL(0, 32768, 1920)   // tile 14, stages tile 15
  TILE_LAST(32768)              // tile 15

  // epilogue: C/D map col = lane&15, row = kq*4 + j (shape-determined)
  float bv[4];
#pragma unroll
  for (int nf = 0; nf < 4; ++nf) bv[nf] = bias[n0 + wc * 64 + nf * 16 + lr];
#pragma unroll
  for (int fr = 0; fr < 8; ++fr) {
#pragma unroll
    for (int j = 0; j < 4; ++j) {
      const int gr = m0 + wr * 128 + fr * 16 + kq * 4 + j;
      float* orow = y + (size_t)gr * N_COLS + n0 + wc * 64 + lr;
#pragma unroll
      for (int nf = 0; nf < 4; ++nf)
        orow[nf * 16] = acc[fr][nf][j] + bv[nf];
    }
  }
}

// =========================================================================
extern "C" void kernel_launch(void* const* d_in, const int* in_sizes, int n_in,
                              void* d_out, int out_size, void* d_ws, size_t ws_size,
                              hipStream_t stream) {
  const float* x    = (const float*)d_in[0];
  const float* wgt  = (const float*)d_in[1];
  const float* bias = (const float*)d_in[2];
  float* y = (float*)d_out;

  unsigned char* xa = (unsigned char*)d_ws;             // 8192*2048 = 16 MB
  unsigned char* wb = xa + (size_t)M_ROWS * KB_ROW;     // 4096*2048 =  8 MB

  binarize_fp4_kernel<<<2048, 256, 0, stream>>>(
      (const float4*)x, (unsigned*)xa, (M_ROWS * K_DIM) / 8);
  binarize_fp4_kernel<<<2048, 256, 0, stream>>>(
      (const float4*)wgt, (unsigned*)wb, (N_COLS * K_DIM) / 8);

  bgemm_fp4_8ph<<<512, 512, 0, stream>>>(xa, wb, bias, y);
}